// Round 18
// baseline (1590.755 us; speedup 1.0000x reference)
//
#include <hip/hip_runtime.h>

// ---------------------------------------------------------------------------
// NeuralSplineCouplingLayer fused kernel (MI355X / gfx950) — round 18
// R12 (640us) = best clean kernel. R17's pair-gemm3 halved A-reads but its
// 8-acc fp32 epilogue spilled (+80MB). R18 achieves the SAME A-read halving
// with FEWER live registers via v_mfma_f32_32x32x16_f16 in gemm3:
//   one A-frag covers all 32 rows -> 2 A-reads + 2 B-reads per 3 MFMAs,
//   accs = 2 x v16f (32 regs) + 4 operands (16) ~ 48 live.
// h2 stored in 32-row-fragment layout (gemm2 epilogue indices only);
// W3 prepped in 32x32 B layout; 32-col chunk tiles (12/13/13/12, trip<=1,
// runtime ntiles). gemm1/2, staging, spline: R12 verbatim.
// ---------------------------------------------------------------------------

typedef _Float16 v8h __attribute__((ext_vector_type(8)));
typedef float v4f __attribute__((ext_vector_type(4)));
typedef float v16f __attribute__((ext_vector_type(16)));

#define ROWS_PER_BLOCK 32
#define NBLOCKS (65536 / ROWS_PER_BLOCK)
#define NWAVES 16

// LDS layout (bytes). inp/h1 planes 16-frag-linear; h2 planes 32-frag-linear.
//   sInpHi [0,      8192)   2 x 4  x 64 x 8
//   sInpLo [8192,  16384)
//   sH1Hi  [16384, 49152)   2 x 16 x 64 x 8
//   sH1Lo  [49152, 81920)
//   sH2Hi  [81920, 114688)  32 kk x 64 lane x 8  (32-row frags)
//   sH2Lo  [114688,147456)
//   sRaw   [0,     53760)   32 x 420 f32 — overlays inp+h1 (dead in phase 3)
#define SMEM_BYTES 147456
#define S_INPLO 8192
#define S_H1HI  16384
#define S_H1LO  49152
#define S_H2HI  81920
#define S_H2LO  114688
#define RAW_STRIDE 420

#define LO_SCALE 2048.f
#define LO_INV   (1.f / 2048.f)

__device__ __forceinline__ void split2(float x, _Float16& hi, _Float16& lo) {
    _Float16 h = (_Float16)x;
    hi = h;
    lo = (_Float16)((x - (float)h) * LO_SCALE);
}
__device__ __forceinline__ float silu_f(float v) {
    return v / (1.f + __expf(-v));
}
__device__ __forceinline__ float softplus_f(float v) {
    return v > 15.f ? v : __logf(1.f + __expf(v));
}

// --- prep: W (K x N) f32 -> 16x16 fragment-contiguous fp16 hi/lo (W1, W2) --
// Bfrag[j][ks][lane][e]: col n = j*16+(lane&15), k = ks*32+((lane>>4)<<3)+e.
__global__ void nscl_prep_frag(const float* __restrict__ src,
                               _Float16* __restrict__ hi, _Float16* __restrict__ lo,
                               int K, int N) {
    int idx = blockIdx.x * blockDim.x + threadIdx.x;
    if (idx >= N * K) return;
    const int e    = idx & 7;
    const int lane = (idx >> 3) & 63;
    const int rem  = idx >> 9;
    const int KS   = K >> 5;
    const int ks   = rem % KS;
    const int j    = rem / KS;
    const int n = j * 16 + (lane & 15);
    const int k = ks * 32 + ((lane >> 4) << 3) + e;
    split2(src[k * N + n], hi[idx], lo[idx]);
}

// --- prep: W3 -> 32x32x16 B-fragment layout --------------------------------
// Bfrag32[j][kk][lane][e]: col n = j*32+(lane&31), k = kk*16+((lane>>5)<<3)+e.
__global__ void nscl_prep_frag32(const float* __restrict__ src,
                                 _Float16* __restrict__ hi, _Float16* __restrict__ lo,
                                 int K, int N) {
    int idx = blockIdx.x * blockDim.x + threadIdx.x;
    if (idx >= N * K) return;
    const int e    = idx & 7;
    const int lane = (idx >> 3) & 63;
    const int rem  = idx >> 9;
    const int KK   = K >> 4;
    const int kk   = rem % KK;
    const int j    = rem / KK;
    const int n = j * 32 + (lane & 31);
    const int k = kk * 16 + ((lane >> 5) << 3) + e;
    split2(src[k * N + n], hi[idx], lo[idx]);
}

// --- split GEMM phase (16x16x32): sOut = act(sA @ W + b) -------------------
// OUT32: write output in 32-row-fragment layout (for h2) instead of 16-frag.
template<int KS, int NPAIRS, bool DOSILU, bool OUT32>
__device__ __forceinline__ void gemm_phase(const _Float16* __restrict__ sAhi,
                                           const _Float16* __restrict__ sAlo,
                                           const _Float16* __restrict__ Bhi,
                                           const _Float16* __restrict__ Blo,
                                           const float* __restrict__ bias,
                                           _Float16* __restrict__ sOutHi,
                                           _Float16* __restrict__ sOutLo,
                                           int wave, int lane) {
    const int lr = lane & 15;
    const int rb = (lane >> 4) << 2;

    for (int p = wave; p < NPAIRS; p += NWAVES) {
        const int j0 = p * 2;
        v4f m00 = {0,0,0,0}, m10 = {0,0,0,0}, m01 = {0,0,0,0}, m11 = {0,0,0,0};
        v4f c00 = {0,0,0,0}, c10 = {0,0,0,0}, c01 = {0,0,0,0}, c11 = {0,0,0,0};
        #pragma unroll
        for (int ks = 0; ks < KS; ++ks) {
            const int ab = (ks * 64 + lane) * 8;
            v8h a0h = *(const v8h*)(sAhi + ab);
            v8h a0l = *(const v8h*)(sAlo + ab);
            v8h a1h = *(const v8h*)(sAhi + KS * 512 + ab);
            v8h a1l = *(const v8h*)(sAlo + KS * 512 + ab);
            const int bo0 = ((j0 * KS + ks) * 64 + lane) * 8;
            const int bo1 = (((j0 + 1) * KS + ks) * 64 + lane) * 8;
            v8h b0h = *(const v8h*)(Bhi + bo0);
            v8h b0l = *(const v8h*)(Blo + bo0);
            v8h b1h = *(const v8h*)(Bhi + bo1);
            v8h b1l = *(const v8h*)(Blo + bo1);
            m00 = __builtin_amdgcn_mfma_f32_16x16x32_f16(a0h, b0h, m00, 0, 0, 0);
            m10 = __builtin_amdgcn_mfma_f32_16x16x32_f16(a1h, b0h, m10, 0, 0, 0);
            m01 = __builtin_amdgcn_mfma_f32_16x16x32_f16(a0h, b1h, m01, 0, 0, 0);
            m11 = __builtin_amdgcn_mfma_f32_16x16x32_f16(a1h, b1h, m11, 0, 0, 0);
            c00 = __builtin_amdgcn_mfma_f32_16x16x32_f16(a0h, b0l, c00, 0, 0, 0);
            c00 = __builtin_amdgcn_mfma_f32_16x16x32_f16(a0l, b0h, c00, 0, 0, 0);
            c10 = __builtin_amdgcn_mfma_f32_16x16x32_f16(a1h, b0l, c10, 0, 0, 0);
            c10 = __builtin_amdgcn_mfma_f32_16x16x32_f16(a1l, b0h, c10, 0, 0, 0);
            c01 = __builtin_amdgcn_mfma_f32_16x16x32_f16(a0h, b1l, c01, 0, 0, 0);
            c01 = __builtin_amdgcn_mfma_f32_16x16x32_f16(a0l, b1h, c01, 0, 0, 0);
            c11 = __builtin_amdgcn_mfma_f32_16x16x32_f16(a1h, b1l, c11, 0, 0, 0);
            c11 = __builtin_amdgcn_mfma_f32_16x16x32_f16(a1l, b1h, c11, 0, 0, 0);
        }
        #pragma unroll
        for (int jj = 0; jj < 2; ++jj) {
            const int C = (j0 + jj) * 16 + lr;
            const float bv = bias[C];
            const v4f mm0 = jj ? m01 : m00;
            const v4f mm1 = jj ? m11 : m10;
            const v4f cc0 = jj ? c01 : c00;
            const v4f cc1 = jj ? c11 : c10;
            #pragma unroll
            for (int r = 0; r < 4; ++r) {
                float v0 = mm0[r] + cc0[r] * LO_INV + bv;
                float v1 = mm1[r] + cc1[r] * LO_INV + bv;
                if (DOSILU) { v0 = silu_f(v0); v1 = silu_f(v1); }
                int off0, off1;
                if (OUT32) {
                    // h2_32: addr(row,k) = ((k>>4)*64 + row + 32*((k>>3)&1))*8 + (k&7)
                    const int base = ((C >> 4) * 64 + 32 * ((C >> 3) & 1)) * 8 + (C & 7);
                    off0 = base + (rb + r) * 8;
                    off1 = base + (16 + rb + r) * 8;
                } else {
                    const int ks2 = C >> 5, g2 = (C >> 3) & 3, e2 = C & 7;
                    off0 = (ks2 * 64 + g2 * 16 + rb + r) * 8 + e2;
                    off1 = ((16 + ks2) * 64 + g2 * 16 + rb + r) * 8 + e2;
                }
                split2(v0, sOutHi[off0], sOutLo[off0]);
                split2(v1, sOutHi[off1], sOutLo[off1]);
            }
        }
    }
}

// --- GEMM3 chunk (32x32x16): ntiles 32-col tiles from tstart, fp32 out -----
__device__ __forceinline__ void gemm3_chunk32(const _Float16* __restrict__ sH2Hi,
                                              const _Float16* __restrict__ sH2Lo,
                                              const _Float16* __restrict__ W3hi,
                                              const _Float16* __restrict__ W3lo,
                                              const float* __restrict__ b3,
                                              float* __restrict__ sRaw,
                                              int tstart, int ntiles,
                                              int wave, int lane) {
    for (int tt = wave; tt < ntiles; tt += NWAVES) {
        const int jt = tstart + tt;
        v16f m = {0,0,0,0,0,0,0,0,0,0,0,0,0,0,0,0};
        v16f c = {0,0,0,0,0,0,0,0,0,0,0,0,0,0,0,0};
        #pragma unroll
        for (int kk = 0; kk < 32; ++kk) {
            const int ab = (kk * 64 + lane) * 8;
            v8h ah = *(const v8h*)(sH2Hi + ab);
            v8h al = *(const v8h*)(sH2Lo + ab);
            const int bo = ((jt * 32 + kk) * 64 + lane) * 8;
            v8h bh = *(const v8h*)(W3hi + bo);
            v8h bl = *(const v8h*)(W3lo + bo);
            m = __builtin_amdgcn_mfma_f32_32x32x16_f16(ah, bh, m, 0, 0, 0);
            c = __builtin_amdgcn_mfma_f32_32x32x16_f16(ah, bl, c, 0, 0, 0);
            c = __builtin_amdgcn_mfma_f32_32x32x16_f16(al, bh, c, 0, 0, 0);
        }
        const int col32 = lane & 31;
        const float bv = b3[jt * 32 + col32];
        const int rbase = (lane >> 5) * 4;
        const int lbase = tt * 32 + col32;
        #pragma unroll
        for (int r = 0; r < 16; ++r) {
            const int row = (r & 3) + 8 * (r >> 2) + rbase;
            sRaw[row * RAW_STRIDE + lbase] = m[r] + c[r] * LO_INV + bv;
        }
    }
}

__global__ __launch_bounds__(1024, 4)
void nscl_fused(const float* __restrict__ xp, const float* __restrict__ ctxp,
                const float* __restrict__ b1, const float* __restrict__ b2,
                const float* __restrict__ b3,
                const _Float16* __restrict__ W1Thi, const _Float16* __restrict__ W1Tlo,
                const _Float16* __restrict__ W2Thi, const _Float16* __restrict__ W2Tlo,
                const _Float16* __restrict__ W3Thi, const _Float16* __restrict__ W3Tlo,
                float* __restrict__ outY, float* __restrict__ outLD) {
    __shared__ __align__(16) char smem[SMEM_BYTES];
    _Float16* sInpHi = (_Float16*)smem;
    _Float16* sInpLo = (_Float16*)(smem + S_INPLO);
    _Float16* sH1Hi  = (_Float16*)(smem + S_H1HI);
    _Float16* sH1Lo  = (_Float16*)(smem + S_H1LO);
    _Float16* sH2Hi  = (_Float16*)(smem + S_H2HI);
    _Float16* sH2Lo  = (_Float16*)(smem + S_H2LO);
    float*    sRaw   = (float*)smem;               // overlay (phase 3)

    const int tid  = threadIdx.x;
    const int lane = tid & 63;
    const int wave = tid >> 6;
    const int row0 = blockIdx.x * ROWS_PER_BLOCK;

    // ---- stage masked input into frag layout (scalar, clean) ---------------
    for (int idx = tid; idx < ROWS_PER_BLOCK * 128; idx += 1024) {
        const int e  = idx & 7;
        const int l  = (idx >> 3) & 63;
        const int ks = (idx >> 9) & 3;
        const int mt = idx >> 11;
        const int row = mt * 16 + (l & 15);
        const int c   = ks * 32 + ((l >> 4) << 3) + e;
        float v;
        if (c < 64) v = (c & 1) ? 0.f : xp[(row0 + row) * 64 + c];
        else        v = ctxp[(row0 + row) * 64 + (c - 64)];
        split2(v, sInpHi[idx], sInpLo[idx]);
    }
    __syncthreads();

    gemm_phase<4, 16, true, false>(sInpHi, sInpLo, W1Thi, W1Tlo, b1,
                                   sH1Hi, sH1Lo, wave, lane);
    __syncthreads();
    gemm_phase<16, 16, true, true>(sH1Hi, sH1Lo, W2Thi, W2Tlo, b2,
                                   sH2Hi, sH2Lo, wave, lane);
    __syncthreads();

    // ---- GEMM3 (32x32 tiles) + spline, 4 chunks of 8 transforms ------------
    const float TB = 5.0f;
    float ldacc = 0.f;
    const int r  = (tid < 256) ? (tid >> 3) : 0;
    const int tl = tid & 7;

    #pragma unroll 1
    for (int ch = 0; ch < 4; ++ch) {
        const int tstart = (47 * ch) >> 2;                       // 0,11,23,35
        const int ntiles = ((376 * (ch + 1) + 31) >> 5) - tstart; // 12,13,13,12
        const int delta  = 376 * ch - 32 * tstart;                // 0,24,16,8
        gemm3_chunk32(sH2Hi, sH2Lo, W3Thi, W3Tlo, b3, sRaw,
                      tstart, ntiles, wave, lane);
        __syncthreads();

        if (tid < 256) {
            const int t = ch * 8 + tl;
            const int g = row0 + r;
            const float* pr = sRaw + r * RAW_STRIDE + delta + tl * 47;

            float mw = -1e30f, mh = -1e30f;
            #pragma unroll
            for (int i = 0; i < 16; ++i) {
                mw = fmaxf(mw, pr[i]);
                mh = fmaxf(mh, pr[16 + i]);
            }
            float wv[16], hv[16];
            float sw = 0.f, sh = 0.f;
            #pragma unroll
            for (int i = 0; i < 16; ++i) {
                wv[i] = __expf(pr[i] - mw);       sw += wv[i];
                hv[i] = __expf(pr[16 + i] - mh);  sh += hv[i];
            }
            const float scw = 10.f / sw;
            const float sch = 10.f / sh;

            const float xt = xp[g * 64 + 2 * t + 1];
            const float xc = fminf(fmaxf(xt, -TB + 1e-6f), TB - 1e-6f);

            float cum = -TB; int cnt = 0;
            #pragma unroll
            for (int i = 0; i < 16; ++i) {
                cum += wv[i] * scw;
                cnt += (cum < xc) ? 1 : 0;
            }
            const int bin = cnt > 15 ? 15 : cnt;

            float w_k = 0.f, cw_k = 0.f, h_k = 0.f, ch_k = 0.f;
            float cw = -TB, chh = -TB;
            #pragma unroll
            for (int i = 0; i < 16; ++i) {
                const float wi = wv[i] * scw;
                const float hi = hv[i] * sch;
                if (i == bin) { w_k = wi; cw_k = cw; h_k = hi; ch_k = chh; }
                cw += wi; chh += hi;
            }

            const float d_k  = (bin == 0)  ? 1.f : softplus_f(pr[31 + bin]);
            const float d_k1 = (bin == 15) ? 1.f : softplus_f(pr[32 + bin]);

            float xi = (xc - cw_k) / w_k;
            xi = fminf(fmaxf(xi, 0.f), 1.f);
            const float om = 1.f - xi;
            const float num = h_k * (d_k * xi * xi + 2.f * xi * om);
            const float den = d_k + (d_k1 + d_k - 2.f) * xi * om;
            const float yv  = ch_k + num / (den + 1e-8f);
            const float dv  = h_k * h_k * (d_k1 * xi * xi + 2.f * xi * om + d_k * om * om)
                              / (den * den * w_k + 1e-8f) + 1e-8f;

            float v = __logf(dv);
            v += __shfl_xor(v, 1);
            v += __shfl_xor(v, 2);
            v += __shfl_xor(v, 4);
            ldacc += v;

            outY[g * 64 + 2 * t]     = xp[g * 64 + 2 * t];
            outY[g * 64 + 2 * t + 1] = yv;
        }
        __syncthreads();
    }

    if (tid < 256 && tl == 0) outLD[row0 + r] = ldacc;
}

extern "C" void kernel_launch(void* const* d_in, const int* in_sizes, int n_in,
                              void* d_out, int out_size, void* d_ws, size_t ws_size,
                              hipStream_t stream) {
    (void)in_sizes; (void)n_in; (void)out_size; (void)ws_size;
    const float* x   = (const float*)d_in[0];
    const float* ctx = (const float*)d_in[1];
    const float* W1  = (const float*)d_in[2];
    const float* b1  = (const float*)d_in[3];
    const float* W2  = (const float*)d_in[4];
    const float* b2  = (const float*)d_in[5];
    const float* W3  = (const float*)d_in[6];
    const float* b3  = (const float*)d_in[7];

    _Float16* base = (_Float16*)d_ws;
    _Float16* W1Thi = base;                    // 512x128   = 65536
    _Float16* W1Tlo = base + 65536;
    _Float16* W2Thi = base + 131072;           // 512x512   = 262144
    _Float16* W2Tlo = base + 393216;
    _Float16* W3Thi = base + 655360;           // 1504x512  = 770048 (32-frag)
    _Float16* W3Tlo = base + 1425408;

    nscl_prep_frag<<<(512 * 128 + 255) / 256, 256, 0, stream>>>(W1, W1Thi, W1Tlo, 128, 512);
    nscl_prep_frag<<<(512 * 512 + 255) / 256, 256, 0, stream>>>(W2, W2Thi, W2Tlo, 512, 512);
    nscl_prep_frag32<<<(512 * 1504 + 255) / 256, 256, 0, stream>>>(W3, W3Thi, W3Tlo, 512, 1504);

    float* outY  = (float*)d_out;
    float* outLD = outY + 65536 * 64;

    nscl_fused<<<NBLOCKS, 1024, 0, stream>>>(x, ctx, b1, b2, b3,
                                             W1Thi, W1Tlo, W2Thi, W2Tlo, W3Thi, W3Tlo,
                                             outY, outLD);
}

// Round 19
// 743.689 us; speedup vs baseline: 2.1390x; 2.1390x over previous
//
#include <hip/hip_runtime.h>

// ---------------------------------------------------------------------------
// NeuralSplineCouplingLayer fused kernel (MI355X / gfx950) — round 19
// R12 (640us) = best. R13-R18: every gemm restructure (trip>1, pair-epilogue,
// 32x32 MFMA, wave-spec) spilled at the pinned VGPR=64 -> skeleton FROZEN.
// R19 = R12 with ONE storage-only change: the spline's wv[16]/hv[16] arrays
// (the remaining 74MB scratch spill) move to dead LDS:
//   RAW_STRIDE 388->384 (384 cols needed exactly), raw = 49152B,
//   sWv[32][256] f32 at 49152..81920 (exact fit in dead inp+h1 region).
// Transposed [coeff][task] layout -> lane-consecutive, conflict-free.
// Control flow, gemm bodies, launch config: R12 byte-identical.
// ---------------------------------------------------------------------------

typedef _Float16 v8h __attribute__((ext_vector_type(8)));
typedef float v4f __attribute__((ext_vector_type(4)));

#define ROWS_PER_BLOCK 32
#define NBLOCKS (65536 / ROWS_PER_BLOCK)
#define NWAVES 16

// LDS layout (bytes). A-planes fragment-linear: plane[mt][ks][lane][8] fp16.
//   sInpHi [0,      8192)   2 x 4  x 64 x 8
//   sInpLo [8192,  16384)
//   sH1Hi  [16384, 49152)   2 x 16 x 64 x 8
//   sH1Lo  [49152, 81920)
//   sH2Hi  [81920, 114688)
//   sH2Lo  [114688,147456)
//   sRaw   [0,     49152)   32 x 384 f32 — overlays inp+h1 (dead in phase 3)
//   sWv    [49152, 81920)   32 x 256 f32 — spline coeff scratch (phase 3)
#define SMEM_BYTES 147456
#define S_INPLO 8192
#define S_H1HI  16384
#define S_H1LO  49152
#define S_H2HI  81920
#define S_H2LO  114688
#define RAW_STRIDE 384
#define S_WV 49152

#define LO_SCALE 2048.f
#define LO_INV   (1.f / 2048.f)

__device__ __forceinline__ void split2(float x, _Float16& hi, _Float16& lo) {
    _Float16 h = (_Float16)x;
    hi = h;
    lo = (_Float16)((x - (float)h) * LO_SCALE);
}
__device__ __forceinline__ float silu_f(float v) {
    return v / (1.f + __expf(-v));
}
__device__ __forceinline__ float softplus_f(float v) {
    return v > 15.f ? v : __logf(1.f + __expf(v));
}

// --- prep: W (K x N) f32 -> fragment-contiguous fp16 hi/lo -----------------
// Bfrag[j][ks][lane][e]: col n = j*16+(lane&15), k = ks*32+((lane>>4)<<3)+e.
__global__ void nscl_prep_frag(const float* __restrict__ src,
                               _Float16* __restrict__ hi, _Float16* __restrict__ lo,
                               int K, int N) {
    int idx = blockIdx.x * blockDim.x + threadIdx.x;
    if (idx >= N * K) return;
    const int e    = idx & 7;
    const int lane = (idx >> 3) & 63;
    const int rem  = idx >> 9;
    const int KS   = K >> 5;
    const int ks   = rem % KS;
    const int j    = rem / KS;
    const int n = j * 16 + (lane & 15);
    const int k = ks * 32 + ((lane >> 4) << 3) + e;
    split2(src[k * N + n], hi[idx], lo[idx]);
}

// --- split GEMM phase: sOut = act(sA @ W + b); A frag-linear ---------------
// 16 waves; each wave owns one 32x32 output patch (2 M-tiles x 2 N-tiles);
// NPAIRS == NWAVES -> trip count 1 per wave (critical for clean codegen).
template<int KS, int NPAIRS, bool DOSILU>
__device__ __forceinline__ void gemm_phase(const _Float16* __restrict__ sAhi,
                                           const _Float16* __restrict__ sAlo,
                                           const _Float16* __restrict__ Bhi,
                                           const _Float16* __restrict__ Blo,
                                           const float* __restrict__ bias,
                                           _Float16* __restrict__ sOutHi,
                                           _Float16* __restrict__ sOutLo,
                                           int wave, int lane) {
    const int lr = lane & 15;
    const int rb = (lane >> 4) << 2;

    for (int p = wave; p < NPAIRS; p += NWAVES) {
        const int j0 = p * 2;
        v4f m00 = {0,0,0,0}, m10 = {0,0,0,0}, m01 = {0,0,0,0}, m11 = {0,0,0,0};
        v4f c00 = {0,0,0,0}, c10 = {0,0,0,0}, c01 = {0,0,0,0}, c11 = {0,0,0,0};
        #pragma unroll
        for (int ks = 0; ks < KS; ++ks) {
            const int ab = (ks * 64 + lane) * 8;
            v8h a0h = *(const v8h*)(sAhi + ab);
            v8h a0l = *(const v8h*)(sAlo + ab);
            v8h a1h = *(const v8h*)(sAhi + KS * 512 + ab);
            v8h a1l = *(const v8h*)(sAlo + KS * 512 + ab);
            const int bo0 = ((j0 * KS + ks) * 64 + lane) * 8;
            const int bo1 = (((j0 + 1) * KS + ks) * 64 + lane) * 8;
            v8h b0h = *(const v8h*)(Bhi + bo0);
            v8h b0l = *(const v8h*)(Blo + bo0);
            v8h b1h = *(const v8h*)(Bhi + bo1);
            v8h b1l = *(const v8h*)(Blo + bo1);
            m00 = __builtin_amdgcn_mfma_f32_16x16x32_f16(a0h, b0h, m00, 0, 0, 0);
            m10 = __builtin_amdgcn_mfma_f32_16x16x32_f16(a1h, b0h, m10, 0, 0, 0);
            m01 = __builtin_amdgcn_mfma_f32_16x16x32_f16(a0h, b1h, m01, 0, 0, 0);
            m11 = __builtin_amdgcn_mfma_f32_16x16x32_f16(a1h, b1h, m11, 0, 0, 0);
            c00 = __builtin_amdgcn_mfma_f32_16x16x32_f16(a0h, b0l, c00, 0, 0, 0);
            c00 = __builtin_amdgcn_mfma_f32_16x16x32_f16(a0l, b0h, c00, 0, 0, 0);
            c10 = __builtin_amdgcn_mfma_f32_16x16x32_f16(a1h, b0l, c10, 0, 0, 0);
            c10 = __builtin_amdgcn_mfma_f32_16x16x32_f16(a1l, b0h, c10, 0, 0, 0);
            c01 = __builtin_amdgcn_mfma_f32_16x16x32_f16(a0h, b1l, c01, 0, 0, 0);
            c01 = __builtin_amdgcn_mfma_f32_16x16x32_f16(a0l, b1h, c01, 0, 0, 0);
            c11 = __builtin_amdgcn_mfma_f32_16x16x32_f16(a1h, b1l, c11, 0, 0, 0);
            c11 = __builtin_amdgcn_mfma_f32_16x16x32_f16(a1l, b1h, c11, 0, 0, 0);
        }
        #pragma unroll
        for (int jj = 0; jj < 2; ++jj) {
            const int C   = (j0 + jj) * 16 + lr;
            const int ks2 = C >> 5, g2 = (C >> 3) & 3, e2 = C & 7;
            const float bv = bias[C];
            const v4f mm0 = jj ? m01 : m00;
            const v4f mm1 = jj ? m11 : m10;
            const v4f cc0 = jj ? c01 : c00;
            const v4f cc1 = jj ? c11 : c10;
            #pragma unroll
            for (int r = 0; r < 4; ++r) {
                float v0 = mm0[r] + cc0[r] * LO_INV + bv;
                float v1 = mm1[r] + cc1[r] * LO_INV + bv;
                if (DOSILU) { v0 = silu_f(v0); v1 = silu_f(v1); }
                const int off0 = (ks2 * 64 + g2 * 16 + rb + r) * 8 + e2;
                const int off1 = ((16 + ks2) * 64 + g2 * 16 + rb + r) * 8 + e2;
                split2(v0, sOutHi[off0], sOutLo[off0]);
                split2(v1, sOutHi[off1], sOutLo[off1]);
            }
        }
    }
}

// --- GEMM3 chunk (split): 24 tiles starting at tile t0, fp32 out -----------
__device__ __forceinline__ void gemm3_chunk(const _Float16* __restrict__ sH2Hi,
                                            const _Float16* __restrict__ sH2Lo,
                                            const _Float16* __restrict__ W3hi,
                                            const _Float16* __restrict__ W3lo,
                                            const float* __restrict__ b3,
                                            float* __restrict__ sRaw,
                                            int t0, int wave, int lane) {
    const int lr = lane & 15;
    const int rb = (lane >> 4) << 2;

    for (int tt = wave; tt < 24; tt += NWAVES) {
        const int jt = t0 + tt;
        v4f m0 = {0,0,0,0}, m1 = {0,0,0,0};
        v4f cc0 = {0,0,0,0}, cc1 = {0,0,0,0};
        #pragma unroll
        for (int ks = 0; ks < 16; ++ks) {
            const int ab = (ks * 64 + lane) * 8;
            v8h a0h = *(const v8h*)(sH2Hi + ab);
            v8h a0l = *(const v8h*)(sH2Lo + ab);
            v8h a1h = *(const v8h*)(sH2Hi + 8192 + ab);
            v8h a1l = *(const v8h*)(sH2Lo + 8192 + ab);
            const int bo = ((jt * 16 + ks) * 64 + lane) * 8;
            v8h bh = *(const v8h*)(W3hi + bo);
            v8h bl = *(const v8h*)(W3lo + bo);
            m0  = __builtin_amdgcn_mfma_f32_16x16x32_f16(a0h, bh, m0, 0, 0, 0);
            m1  = __builtin_amdgcn_mfma_f32_16x16x32_f16(a1h, bh, m1, 0, 0, 0);
            cc0 = __builtin_amdgcn_mfma_f32_16x16x32_f16(a0h, bl, cc0, 0, 0, 0);
            cc0 = __builtin_amdgcn_mfma_f32_16x16x32_f16(a0l, bh, cc0, 0, 0, 0);
            cc1 = __builtin_amdgcn_mfma_f32_16x16x32_f16(a1h, bl, cc1, 0, 0, 0);
            cc1 = __builtin_amdgcn_mfma_f32_16x16x32_f16(a1l, bh, cc1, 0, 0, 0);
        }
        const int col  = jt * 16 + lr;      // < 1504 always (94 tiles exactly)
        const int lcol = tt * 16 + lr;
        const float bv = b3[col];
        #pragma unroll
        for (int r = 0; r < 4; ++r) {
            sRaw[(rb + r) * RAW_STRIDE + lcol]      = m0[r] + cc0[r] * LO_INV + bv;
            sRaw[(16 + rb + r) * RAW_STRIDE + lcol] = m1[r] + cc1[r] * LO_INV + bv;
        }
    }
}

__global__ __launch_bounds__(1024, 4)
void nscl_fused(const float* __restrict__ xp, const float* __restrict__ ctxp,
                const float* __restrict__ b1, const float* __restrict__ b2,
                const float* __restrict__ b3,
                const _Float16* __restrict__ W1Thi, const _Float16* __restrict__ W1Tlo,
                const _Float16* __restrict__ W2Thi, const _Float16* __restrict__ W2Tlo,
                const _Float16* __restrict__ W3Thi, const _Float16* __restrict__ W3Tlo,
                float* __restrict__ outY, float* __restrict__ outLD) {
    __shared__ __align__(16) char smem[SMEM_BYTES];
    _Float16* sInpHi = (_Float16*)smem;
    _Float16* sInpLo = (_Float16*)(smem + S_INPLO);
    _Float16* sH1Hi  = (_Float16*)(smem + S_H1HI);
    _Float16* sH1Lo  = (_Float16*)(smem + S_H1LO);
    _Float16* sH2Hi  = (_Float16*)(smem + S_H2HI);
    _Float16* sH2Lo  = (_Float16*)(smem + S_H2LO);
    float*    sRaw   = (float*)smem;                 // overlay (phase 3)
    float*    sWv    = (float*)(smem + S_WV);        // spline scratch (phase 3)

    const int tid  = threadIdx.x;
    const int lane = tid & 63;
    const int wave = tid >> 6;
    const int row0 = blockIdx.x * ROWS_PER_BLOCK;

    // ---- stage masked input into frag layout (scalar, clean) ---------------
    for (int idx = tid; idx < ROWS_PER_BLOCK * 128; idx += 1024) {
        const int e  = idx & 7;
        const int l  = (idx >> 3) & 63;
        const int ks = (idx >> 9) & 3;
        const int mt = idx >> 11;
        const int row = mt * 16 + (l & 15);
        const int c   = ks * 32 + ((l >> 4) << 3) + e;
        float v;
        if (c < 64) v = (c & 1) ? 0.f : xp[(row0 + row) * 64 + c];
        else        v = ctxp[(row0 + row) * 64 + (c - 64)];
        split2(v, sInpHi[idx], sInpLo[idx]);
    }
    __syncthreads();

    gemm_phase<4, 16, true>(sInpHi, sInpLo, W1Thi, W1Tlo, b1,
                            sH1Hi, sH1Lo, wave, lane);
    __syncthreads();
    gemm_phase<16, 16, true>(sH1Hi, sH1Lo, W2Thi, W2Tlo, b2,
                             sH2Hi, sH2Lo, wave, lane);
    __syncthreads();

    // ---- GEMM3 + spline, 4 chunks of 8 transforms --------------------------
    const float TB = 5.0f;
    float ldacc = 0.f;
    const int r  = (tid < 256) ? (tid >> 3) : 0;
    const int tl = tid & 7;
    const int t0s[4] = {0, 23, 47, 70};   // tile-aligned chunk starts

    #pragma unroll 1
    for (int ch = 0; ch < 4; ++ch) {
        gemm3_chunk(sH2Hi, sH2Lo, W3Thi, W3Tlo, b3, sRaw, t0s[ch], wave, lane);
        __syncthreads();

        if (tid < 256) {
            const int t = ch * 8 + tl;
            const int g = row0 + r;
            const float* pr = sRaw + r * RAW_STRIDE + ((ch & 1) ? 8 : 0) + tl * 47;
            float* wv = sWv + tid;                    // [i*256 + tid]
            float* hv = sWv + 16 * 256 + tid;

            float mw = -1e30f, mh = -1e30f;
            #pragma unroll
            for (int i = 0; i < 16; ++i) {
                mw = fmaxf(mw, pr[i]);
                mh = fmaxf(mh, pr[16 + i]);
            }
            float sw = 0.f, sh = 0.f;
            #pragma unroll
            for (int i = 0; i < 16; ++i) {
                const float we = __expf(pr[i] - mw);
                const float he = __expf(pr[16 + i] - mh);
                wv[i * 256] = we;  sw += we;
                hv[i * 256] = he;  sh += he;
            }
            const float scw = 10.f / sw;
            const float sch = 10.f / sh;

            const float xt = xp[g * 64 + 2 * t + 1];
            const float xc = fminf(fmaxf(xt, -TB + 1e-6f), TB - 1e-6f);

            float cum = -TB; int cnt = 0;
            #pragma unroll
            for (int i = 0; i < 16; ++i) {
                cum += wv[i * 256] * scw;
                cnt += (cum < xc) ? 1 : 0;
            }
            const int bin = cnt > 15 ? 15 : cnt;

            float w_k = 0.f, cw_k = 0.f, h_k = 0.f, ch_k = 0.f;
            float cw = -TB, chh = -TB;
            #pragma unroll
            for (int i = 0; i < 16; ++i) {
                const float wi = wv[i * 256] * scw;
                const float hi = hv[i * 256] * sch;
                if (i == bin) { w_k = wi; cw_k = cw; h_k = hi; ch_k = chh; }
                cw += wi; chh += hi;
            }

            const float d_k  = (bin == 0)  ? 1.f : softplus_f(pr[31 + bin]);
            const float d_k1 = (bin == 15) ? 1.f : softplus_f(pr[32 + bin]);

            float xi = (xc - cw_k) / w_k;
            xi = fminf(fmaxf(xi, 0.f), 1.f);
            const float om = 1.f - xi;
            const float num = h_k * (d_k * xi * xi + 2.f * xi * om);
            const float den = d_k + (d_k1 + d_k - 2.f) * xi * om;
            const float yv  = ch_k + num / (den + 1e-8f);
            const float dv  = h_k * h_k * (d_k1 * xi * xi + 2.f * xi * om + d_k * om * om)
                              / (den * den * w_k + 1e-8f) + 1e-8f;

            float v = __logf(dv);
            v += __shfl_xor(v, 1);
            v += __shfl_xor(v, 2);
            v += __shfl_xor(v, 4);
            ldacc += v;

            outY[g * 64 + 2 * t]     = xp[g * 64 + 2 * t];
            outY[g * 64 + 2 * t + 1] = yv;
        }
        __syncthreads();
    }

    if (tid < 256 && tl == 0) outLD[row0 + r] = ldacc;
}

extern "C" void kernel_launch(void* const* d_in, const int* in_sizes, int n_in,
                              void* d_out, int out_size, void* d_ws, size_t ws_size,
                              hipStream_t stream) {
    (void)in_sizes; (void)n_in; (void)out_size; (void)ws_size;
    const float* x   = (const float*)d_in[0];
    const float* ctx = (const float*)d_in[1];
    const float* W1  = (const float*)d_in[2];
    const float* b1  = (const float*)d_in[3];
    const float* W2  = (const float*)d_in[4];
    const float* b2  = (const float*)d_in[5];
    const float* W3  = (const float*)d_in[6];
    const float* b3  = (const float*)d_in[7];

    _Float16* base = (_Float16*)d_ws;
    _Float16* W1Thi = base;                    // 512x128   = 65536
    _Float16* W1Tlo = base + 65536;
    _Float16* W2Thi = base + 131072;           // 512x512   = 262144
    _Float16* W2Tlo = base + 393216;
    _Float16* W3Thi = base + 655360;           // 1504x512  = 770048
    _Float16* W3Tlo = base + 1425408;

    nscl_prep_frag<<<(512 * 128 + 255) / 256, 256, 0, stream>>>(W1, W1Thi, W1Tlo, 128, 512);
    nscl_prep_frag<<<(512 * 512 + 255) / 256, 256, 0, stream>>>(W2, W2Thi, W2Tlo, 512, 512);
    nscl_prep_frag<<<(512 * 1504 + 255) / 256, 256, 0, stream>>>(W3, W3Thi, W3Tlo, 512, 1504);

    float* outY  = (float*)d_out;
    float* outLD = outY + 65536 * 64;

    nscl_fused<<<NBLOCKS, 1024, 0, stream>>>(x, ctx, b1, b2, b3,
                                             W1Thi, W1Tlo, W2Thi, W2Tlo, W3Thi, W3Tlo,
                                             outY, outLD);
}

// Round 20
// 634.657 us; speedup vs baseline: 2.5065x; 1.1718x over previous
//
#include <hip/hip_runtime.h>

// ---------------------------------------------------------------------------
// NeuralSplineCouplingLayer fused kernel (MI355X / gfx950) — round 20
// R12 (640us) = best. Unified-regfile analysis: __launch_bounds__(1024,4)
// sets budget 512/4 = 128 TOTAL regs = 64 arch VGPR + 64 acc AGPR -> the
// spline's 32-float arrays + gemm operands overflow the 64 arch half ->
// the persistent 74MB spill. (512,2) was honored with 128 arch (R3/R10),
// so the API works. LDS (147KB) caps occupancy at 1 block/CU = 4 waves/EU
// PHYSICALLY, so requesting min 2 waves/EU (budget 256) is free as long as
// actual usage stays <=128 total — R12's peak is ~96.
// R20 = R12 byte-identical except __launch_bounds__(1024, 2).
// ---------------------------------------------------------------------------

typedef _Float16 v8h __attribute__((ext_vector_type(8)));
typedef float v4f __attribute__((ext_vector_type(4)));

#define ROWS_PER_BLOCK 32
#define NBLOCKS (65536 / ROWS_PER_BLOCK)
#define NWAVES 16

// LDS layout (bytes). A-planes fragment-linear: plane[mt][ks][lane][8] fp16.
//   sInpHi [0,      8192)   2 x 4  x 64 x 8
//   sInpLo [8192,  16384)
//   sH1Hi  [16384, 49152)   2 x 16 x 64 x 8
//   sH1Lo  [49152, 81920)
//   sH2Hi  [81920, 114688)
//   sH2Lo  [114688,147456)
//   sRaw   [0,     49664)   32 x 388 f32 — overlays inp+h1 (dead in phase 3)
#define SMEM_BYTES 147456
#define S_INPLO 8192
#define S_H1HI  16384
#define S_H1LO  49152
#define S_H2HI  81920
#define S_H2LO  114688
#define RAW_STRIDE 388

#define LO_SCALE 2048.f
#define LO_INV   (1.f / 2048.f)

__device__ __forceinline__ void split2(float x, _Float16& hi, _Float16& lo) {
    _Float16 h = (_Float16)x;
    hi = h;
    lo = (_Float16)((x - (float)h) * LO_SCALE);
}
__device__ __forceinline__ float silu_f(float v) {
    return v / (1.f + __expf(-v));
}
__device__ __forceinline__ float softplus_f(float v) {
    return v > 15.f ? v : __logf(1.f + __expf(v));
}

// --- prep: W (K x N) f32 -> fragment-contiguous fp16 hi/lo -----------------
// Bfrag[j][ks][lane][e]: col n = j*16+(lane&15), k = ks*32+((lane>>4)<<3)+e.
__global__ void nscl_prep_frag(const float* __restrict__ src,
                               _Float16* __restrict__ hi, _Float16* __restrict__ lo,
                               int K, int N) {
    int idx = blockIdx.x * blockDim.x + threadIdx.x;
    if (idx >= N * K) return;
    const int e    = idx & 7;
    const int lane = (idx >> 3) & 63;
    const int rem  = idx >> 9;
    const int KS   = K >> 5;
    const int ks   = rem % KS;
    const int j    = rem / KS;
    const int n = j * 16 + (lane & 15);
    const int k = ks * 32 + ((lane >> 4) << 3) + e;
    split2(src[k * N + n], hi[idx], lo[idx]);
}

// --- split GEMM phase: sOut = act(sA @ W + b); A frag-linear ---------------
// 16 waves; each wave owns one 32x32 output patch (2 M-tiles x 2 N-tiles);
// NPAIRS == NWAVES -> trip count 1 per wave (critical for clean codegen).
template<int KS, int NPAIRS, bool DOSILU>
__device__ __forceinline__ void gemm_phase(const _Float16* __restrict__ sAhi,
                                           const _Float16* __restrict__ sAlo,
                                           const _Float16* __restrict__ Bhi,
                                           const _Float16* __restrict__ Blo,
                                           const float* __restrict__ bias,
                                           _Float16* __restrict__ sOutHi,
                                           _Float16* __restrict__ sOutLo,
                                           int wave, int lane) {
    const int lr = lane & 15;
    const int rb = (lane >> 4) << 2;

    for (int p = wave; p < NPAIRS; p += NWAVES) {
        const int j0 = p * 2;
        v4f m00 = {0,0,0,0}, m10 = {0,0,0,0}, m01 = {0,0,0,0}, m11 = {0,0,0,0};
        v4f c00 = {0,0,0,0}, c10 = {0,0,0,0}, c01 = {0,0,0,0}, c11 = {0,0,0,0};
        #pragma unroll
        for (int ks = 0; ks < KS; ++ks) {
            const int ab = (ks * 64 + lane) * 8;
            v8h a0h = *(const v8h*)(sAhi + ab);
            v8h a0l = *(const v8h*)(sAlo + ab);
            v8h a1h = *(const v8h*)(sAhi + KS * 512 + ab);
            v8h a1l = *(const v8h*)(sAlo + KS * 512 + ab);
            const int bo0 = ((j0 * KS + ks) * 64 + lane) * 8;
            const int bo1 = (((j0 + 1) * KS + ks) * 64 + lane) * 8;
            v8h b0h = *(const v8h*)(Bhi + bo0);
            v8h b0l = *(const v8h*)(Blo + bo0);
            v8h b1h = *(const v8h*)(Bhi + bo1);
            v8h b1l = *(const v8h*)(Blo + bo1);
            m00 = __builtin_amdgcn_mfma_f32_16x16x32_f16(a0h, b0h, m00, 0, 0, 0);
            m10 = __builtin_amdgcn_mfma_f32_16x16x32_f16(a1h, b0h, m10, 0, 0, 0);
            m01 = __builtin_amdgcn_mfma_f32_16x16x32_f16(a0h, b1h, m01, 0, 0, 0);
            m11 = __builtin_amdgcn_mfma_f32_16x16x32_f16(a1h, b1h, m11, 0, 0, 0);
            c00 = __builtin_amdgcn_mfma_f32_16x16x32_f16(a0h, b0l, c00, 0, 0, 0);
            c00 = __builtin_amdgcn_mfma_f32_16x16x32_f16(a0l, b0h, c00, 0, 0, 0);
            c10 = __builtin_amdgcn_mfma_f32_16x16x32_f16(a1h, b0l, c10, 0, 0, 0);
            c10 = __builtin_amdgcn_mfma_f32_16x16x32_f16(a1l, b0h, c10, 0, 0, 0);
            c01 = __builtin_amdgcn_mfma_f32_16x16x32_f16(a0h, b1l, c01, 0, 0, 0);
            c01 = __builtin_amdgcn_mfma_f32_16x16x32_f16(a0l, b1h, c01, 0, 0, 0);
            c11 = __builtin_amdgcn_mfma_f32_16x16x32_f16(a1h, b1l, c11, 0, 0, 0);
            c11 = __builtin_amdgcn_mfma_f32_16x16x32_f16(a1l, b1h, c11, 0, 0, 0);
        }
        #pragma unroll
        for (int jj = 0; jj < 2; ++jj) {
            const int C   = (j0 + jj) * 16 + lr;
            const int ks2 = C >> 5, g2 = (C >> 3) & 3, e2 = C & 7;
            const float bv = bias[C];
            const v4f mm0 = jj ? m01 : m00;
            const v4f mm1 = jj ? m11 : m10;
            const v4f cc0 = jj ? c01 : c00;
            const v4f cc1 = jj ? c11 : c10;
            #pragma unroll
            for (int r = 0; r < 4; ++r) {
                float v0 = mm0[r] + cc0[r] * LO_INV + bv;
                float v1 = mm1[r] + cc1[r] * LO_INV + bv;
                if (DOSILU) { v0 = silu_f(v0); v1 = silu_f(v1); }
                const int off0 = (ks2 * 64 + g2 * 16 + rb + r) * 8 + e2;
                const int off1 = ((16 + ks2) * 64 + g2 * 16 + rb + r) * 8 + e2;
                split2(v0, sOutHi[off0], sOutLo[off0]);
                split2(v1, sOutHi[off1], sOutLo[off1]);
            }
        }
    }
}

// --- GEMM3 chunk (split): 24 tiles starting at tile t0, fp32 out -----------
__device__ __forceinline__ void gemm3_chunk(const _Float16* __restrict__ sH2Hi,
                                            const _Float16* __restrict__ sH2Lo,
                                            const _Float16* __restrict__ W3hi,
                                            const _Float16* __restrict__ W3lo,
                                            const float* __restrict__ b3,
                                            float* __restrict__ sRaw,
                                            int t0, int wave, int lane) {
    const int lr = lane & 15;
    const int rb = (lane >> 4) << 2;

    for (int tt = wave; tt < 24; tt += NWAVES) {
        const int jt = t0 + tt;
        v4f m0 = {0,0,0,0}, m1 = {0,0,0,0};
        v4f cc0 = {0,0,0,0}, cc1 = {0,0,0,0};
        #pragma unroll
        for (int ks = 0; ks < 16; ++ks) {
            const int ab = (ks * 64 + lane) * 8;
            v8h a0h = *(const v8h*)(sH2Hi + ab);
            v8h a0l = *(const v8h*)(sH2Lo + ab);
            v8h a1h = *(const v8h*)(sH2Hi + 8192 + ab);
            v8h a1l = *(const v8h*)(sH2Lo + 8192 + ab);
            const int bo = ((jt * 16 + ks) * 64 + lane) * 8;
            v8h bh = *(const v8h*)(W3hi + bo);
            v8h bl = *(const v8h*)(W3lo + bo);
            m0  = __builtin_amdgcn_mfma_f32_16x16x32_f16(a0h, bh, m0, 0, 0, 0);
            m1  = __builtin_amdgcn_mfma_f32_16x16x32_f16(a1h, bh, m1, 0, 0, 0);
            cc0 = __builtin_amdgcn_mfma_f32_16x16x32_f16(a0h, bl, cc0, 0, 0, 0);
            cc0 = __builtin_amdgcn_mfma_f32_16x16x32_f16(a0l, bh, cc0, 0, 0, 0);
            cc1 = __builtin_amdgcn_mfma_f32_16x16x32_f16(a1h, bl, cc1, 0, 0, 0);
            cc1 = __builtin_amdgcn_mfma_f32_16x16x32_f16(a1l, bh, cc1, 0, 0, 0);
        }
        const int col  = jt * 16 + lr;      // < 1504 always (94 tiles exactly)
        const int lcol = tt * 16 + lr;
        const float bv = b3[col];
        #pragma unroll
        for (int r = 0; r < 4; ++r) {
            sRaw[(rb + r) * RAW_STRIDE + lcol]      = m0[r] + cc0[r] * LO_INV + bv;
            sRaw[(16 + rb + r) * RAW_STRIDE + lcol] = m1[r] + cc1[r] * LO_INV + bv;
        }
    }
}

__global__ __launch_bounds__(1024, 2)
void nscl_fused(const float* __restrict__ xp, const float* __restrict__ ctxp,
                const float* __restrict__ b1, const float* __restrict__ b2,
                const float* __restrict__ b3,
                const _Float16* __restrict__ W1Thi, const _Float16* __restrict__ W1Tlo,
                const _Float16* __restrict__ W2Thi, const _Float16* __restrict__ W2Tlo,
                const _Float16* __restrict__ W3Thi, const _Float16* __restrict__ W3Tlo,
                float* __restrict__ outY, float* __restrict__ outLD) {
    __shared__ __align__(16) char smem[SMEM_BYTES];
    _Float16* sInpHi = (_Float16*)smem;
    _Float16* sInpLo = (_Float16*)(smem + S_INPLO);
    _Float16* sH1Hi  = (_Float16*)(smem + S_H1HI);
    _Float16* sH1Lo  = (_Float16*)(smem + S_H1LO);
    _Float16* sH2Hi  = (_Float16*)(smem + S_H2HI);
    _Float16* sH2Lo  = (_Float16*)(smem + S_H2LO);
    float*    sRaw   = (float*)smem;               // overlay (phase 3)

    const int tid  = threadIdx.x;
    const int lane = tid & 63;
    const int wave = tid >> 6;
    const int row0 = blockIdx.x * ROWS_PER_BLOCK;

    // ---- stage masked input into frag layout (scalar, clean) ---------------
    for (int idx = tid; idx < ROWS_PER_BLOCK * 128; idx += 1024) {
        const int e  = idx & 7;
        const int l  = (idx >> 3) & 63;
        const int ks = (idx >> 9) & 3;
        const int mt = idx >> 11;
        const int row = mt * 16 + (l & 15);
        const int c   = ks * 32 + ((l >> 4) << 3) + e;
        float v;
        if (c < 64) v = (c & 1) ? 0.f : xp[(row0 + row) * 64 + c];
        else        v = ctxp[(row0 + row) * 64 + (c - 64)];
        split2(v, sInpHi[idx], sInpLo[idx]);
    }
    __syncthreads();

    gemm_phase<4, 16, true>(sInpHi, sInpLo, W1Thi, W1Tlo, b1,
                            sH1Hi, sH1Lo, wave, lane);
    __syncthreads();
    gemm_phase<16, 16, true>(sH1Hi, sH1Lo, W2Thi, W2Tlo, b2,
                             sH2Hi, sH2Lo, wave, lane);
    __syncthreads();

    // ---- GEMM3 + spline, 4 chunks of 8 transforms --------------------------
    const float TB = 5.0f;
    float ldacc = 0.f;
    const int r  = (tid < 256) ? (tid >> 3) : 0;
    const int tl = tid & 7;
    const int t0s[4] = {0, 23, 47, 70};   // tile-aligned chunk starts

    #pragma unroll 1
    for (int ch = 0; ch < 4; ++ch) {
        gemm3_chunk(sH2Hi, sH2Lo, W3Thi, W3Tlo, b3, sRaw, t0s[ch], wave, lane);
        __syncthreads();

        if (tid < 256) {
            const int t = ch * 8 + tl;
            const int g = row0 + r;
            const float* pr = sRaw + r * RAW_STRIDE + ((ch & 1) ? 8 : 0) + tl * 47;

            float mw = -1e30f, mh = -1e30f;
            #pragma unroll
            for (int i = 0; i < 16; ++i) {
                mw = fmaxf(mw, pr[i]);
                mh = fmaxf(mh, pr[16 + i]);
            }
            float wv[16], hv[16];
            float sw = 0.f, sh = 0.f;
            #pragma unroll
            for (int i = 0; i < 16; ++i) {
                wv[i] = __expf(pr[i] - mw);       sw += wv[i];
                hv[i] = __expf(pr[16 + i] - mh);  sh += hv[i];
            }
            const float scw = 10.f / sw;
            const float sch = 10.f / sh;

            const float xt = xp[g * 64 + 2 * t + 1];
            const float xc = fminf(fmaxf(xt, -TB + 1e-6f), TB - 1e-6f);

            float cum = -TB; int cnt = 0;
            #pragma unroll
            for (int i = 0; i < 16; ++i) {
                cum += wv[i] * scw;
                cnt += (cum < xc) ? 1 : 0;
            }
            const int bin = cnt > 15 ? 15 : cnt;

            float w_k = 0.f, cw_k = 0.f, h_k = 0.f, ch_k = 0.f;
            float cw = -TB, chh = -TB;
            #pragma unroll
            for (int i = 0; i < 16; ++i) {
                const float wi = wv[i] * scw;
                const float hi = hv[i] * sch;
                if (i == bin) { w_k = wi; cw_k = cw; h_k = hi; ch_k = chh; }
                cw += wi; chh += hi;
            }

            const float d_k  = (bin == 0)  ? 1.f : softplus_f(pr[31 + bin]);
            const float d_k1 = (bin == 15) ? 1.f : softplus_f(pr[32 + bin]);

            float xi = (xc - cw_k) / w_k;
            xi = fminf(fmaxf(xi, 0.f), 1.f);
            const float om = 1.f - xi;
            const float num = h_k * (d_k * xi * xi + 2.f * xi * om);
            const float den = d_k + (d_k1 + d_k - 2.f) * xi * om;
            const float yv  = ch_k + num / (den + 1e-8f);
            const float dv  = h_k * h_k * (d_k1 * xi * xi + 2.f * xi * om + d_k * om * om)
                              / (den * den * w_k + 1e-8f) + 1e-8f;

            float v = __logf(dv);
            v += __shfl_xor(v, 1);
            v += __shfl_xor(v, 2);
            v += __shfl_xor(v, 4);
            ldacc += v;

            outY[g * 64 + 2 * t]     = xp[g * 64 + 2 * t];
            outY[g * 64 + 2 * t + 1] = yv;
        }
        __syncthreads();
    }

    if (tid < 256 && tl == 0) outLD[row0 + r] = ldacc;
}

extern "C" void kernel_launch(void* const* d_in, const int* in_sizes, int n_in,
                              void* d_out, int out_size, void* d_ws, size_t ws_size,
                              hipStream_t stream) {
    (void)in_sizes; (void)n_in; (void)out_size; (void)ws_size;
    const float* x   = (const float*)d_in[0];
    const float* ctx = (const float*)d_in[1];
    const float* W1  = (const float*)d_in[2];
    const float* b1  = (const float*)d_in[3];
    const float* W2  = (const float*)d_in[4];
    const float* b2  = (const float*)d_in[5];
    const float* W3  = (const float*)d_in[6];
    const float* b3  = (const float*)d_in[7];

    _Float16* base = (_Float16*)d_ws;
    _Float16* W1Thi = base;                    // 512x128   = 65536
    _Float16* W1Tlo = base + 65536;
    _Float16* W2Thi = base + 131072;           // 512x512   = 262144
    _Float16* W2Tlo = base + 393216;
    _Float16* W3Thi = base + 655360;           // 1504x512  = 770048
    _Float16* W3Tlo = base + 1425408;

    nscl_prep_frag<<<(512 * 128 + 255) / 256, 256, 0, stream>>>(W1, W1Thi, W1Tlo, 128, 512);
    nscl_prep_frag<<<(512 * 512 + 255) / 256, 256, 0, stream>>>(W2, W2Thi, W2Tlo, 512, 512);
    nscl_prep_frag<<<(512 * 1504 + 255) / 256, 256, 0, stream>>>(W3, W3Thi, W3Tlo, 512, 1504);

    float* outY  = (float*)d_out;
    float* outLD = outY + 65536 * 64;

    nscl_fused<<<NBLOCKS, 1024, 0, stream>>>(x, ctx, b1, b2, b3,
                                             W1Thi, W1Tlo, W2Thi, W2Tlo, W3Thi, W3Tlo,
                                             outY, outLD);
}